// Round 2
// baseline (92.504 us; speedup 1.0000x reference)
//
#include <hip/hip_runtime.h>

// Problem constants (B, N, D, H) from reference: (2, 1024, 128, 64)
#define Bb 2
#define Nn 1024
#define Dd 128
#define Hh 64

typedef float v2f __attribute__((ext_vector_type(2)));

// ---------------------------------------------------------------------------
// Kernel 1: P'[b][r][n], Q'[b][r][n] where r = sign-sorted permutation of h.
//   p[h][n] = (sum_d E[b,n,d]*W1[h,d]       + b1[h]) * |w2[h]|
//   q[h][n] = (sum_d E[b,n,d]*W1[h,128+d])           * |w2[h]|
// Rows with w2[h] >= 0 land at rank(h) in [0,nPos); negatives after.
// k2 then computes  edge = b2 + sum_{r<nPos} relu(p+q) - sum_{r>=nPos} relu(p+q)
// which equals b2 + sum_h w2[h]*relu(ai+aj+b1)  (relu positive homogeneity).
//
// Grid: (4 o-tiles of 32, 16 n-tiles of 64, B).  Block: 256.
// o in [0,64) -> P rows (h=o); o in [64,128) -> Q rows (h=o-64).
// E tile in LDS with d-chunk swizzle so inner reads are 2-way-free b128;
// W1 fragments read from global (L1-resident, 4 addrs/wave broadcast).
// ---------------------------------------------------------------------------
#define ELS 132   // words per n-row (128 data + pad), 16B-aligned
__global__ __launch_bounds__(256)
void k1_proj(const float* __restrict__ E, const float* __restrict__ W1,
             const float* __restrict__ b1, const float* __restrict__ W2,
             float* __restrict__ Pt, float* __restrict__ Qt) {
  __shared__ float El[64 * ELS];   // [n][d], phys chunk = (d/4 + n/4) & 31

  const int t = threadIdx.x;
  const int oBase = blockIdx.x * 32;   // 0,32 -> P; 64,96 -> Q
  const int nBase = blockIdx.y * 64;
  const int b = blockIdx.z;

  // Stage E tile (64 n x 128 d) with swizzled d-chunks.
  const float* esrc = E + ((size_t)b * Nn + nBase) * Dd;
  #pragma unroll
  for (int k = 0; k < 8; ++k) {
    int q = t + k * 256;
    int n = q >> 5;                 // 0..63
    int c4 = q & 31;                // d-chunk 0..31
    float4 v = *(const float4*)(esrc + n * Dd + (c4 << 2));
    int pc = (c4 + (n >> 2)) & 31;  // swizzled chunk
    *(float4*)&El[n * ELS + (pc << 2)] = v;
  }
  __syncthreads();

  const int tn = t & 15;        // n-quad (4 nodes)
  const int to = t >> 4;        // o-pair index 0..15
  const int o0 = oBase + to * 2;
  const bool isP = (oBase < Hh);
  const int h0 = isP ? o0 : (o0 - Hh);
  // W1 row fragments for the two output units
  const float* w0 = W1 + h0 * (2 * Dd) + (isP ? 0 : Dd);
  const float* w1 = w0 + 2 * Dd;

  v2f acc[4][2] = {};
  const int rowb = 4 * tn * ELS;
  #pragma unroll 4
  for (int d = 0; d < 128; d += 4) {
    int co = (((d >> 2) + tn) & 31) << 2;
    float4 wa = *(const float4*)(w0 + d);
    float4 wb = *(const float4*)(w1 + d);
    v2f wa01 = {wa.x, wa.y}, wa23 = {wa.z, wa.w};
    v2f wb01 = {wb.x, wb.y}, wb23 = {wb.z, wb.w};
    #pragma unroll
    for (int a = 0; a < 4; ++a) {
      float4 e4 = *(const float4*)&El[rowb + a * ELS + co];
      v2f e01 = {e4.x, e4.y}, e23 = {e4.z, e4.w};
      acc[a][0] = __builtin_elementwise_fma(e01, wa01,
                  __builtin_elementwise_fma(e23, wa23, acc[a][0]));
      acc[a][1] = __builtin_elementwise_fma(e01, wb01,
                  __builtin_elementwise_fma(e23, wb23, acc[a][1]));
    }
  }

  // Sign-sorted permutation of h (all waves compute the same 64-bit mask).
  unsigned long long mask = __ballot(W2[t & 63] >= 0.0f);
  int nPos = __popcll(mask);

  #pragma unroll
  for (int oj = 0; oj < 2; ++oj) {
    int h = h0 + oj;
    float w2h = W2[h];
    unsigned long long below = mask & ((1ull << h) - 1ull);
    int nb = __popcll(below);
    int row = (w2h >= 0.0f) ? nb : (nPos + (h - nb));
    float s = fabsf(w2h);
    float d0 = acc[0][oj].x + acc[0][oj].y;
    float d1 = acc[1][oj].x + acc[1][oj].y;
    float d2 = acc[2][oj].x + acc[2][oj].y;
    float d3 = acc[3][oj].x + acc[3][oj].y;
    float4 v;
    if (isP) {
      float bb = b1[h];
      v = make_float4((d0 + bb) * s, (d1 + bb) * s, (d2 + bb) * s, (d3 + bb) * s);
    } else {
      v = make_float4(d0 * s, d1 * s, d2 * s, d3 * s);
    }
    float* base = isP ? Pt : Qt;
    *(float4*)(base + ((size_t)b * Hh + row) * Nn + nBase + tn * 4) = v;
  }
}

// ---------------------------------------------------------------------------
// Kernel 2: edge[b,i,j] = b2 + sum_{r<nPos} relu(p+q) - sum_{r>=nPos} relu(p+q)
// 64i x 128j tile per block; 4i x 8j per thread; packed float2 math.
// Q tile split into two 68-stride half-tiles (j%8<4 -> A, else B) so all
// fragment reads are 2-way-bank-aliased b128 (free).  No w2 in the loop.
// Grid: (8 j-tiles, 16 i-tiles, B).  Block: 256.  LDS: 3*17.4KB = 52KB.
// ---------------------------------------------------------------------------
__global__ __launch_bounds__(256)
void k2_edge(const float* __restrict__ Pt, const float* __restrict__ Qt,
             const float* __restrict__ W2, const float* __restrict__ b2,
             float* __restrict__ edge) {
  __shared__ float Pl[64 * 68];
  __shared__ float Qs[2 * 64 * 68];   // [0]=A (j%8 in 0..3), [1]=B (j%8 in 4..7)

  const int t = threadIdx.x;
  const int jBase = blockIdx.x * 128;
  const int iBase = blockIdx.y * 64;
  const int b = blockIdx.z;

  // Stage P: 64h x 64i.
  #pragma unroll
  for (int k = 0; k < 4; ++k) {
    int q = t + k * 256;
    int h = q >> 4;
    int c = (q & 15) << 2;
    *(float4*)&Pl[h * 68 + c] =
        *(const float4*)(Pt + ((size_t)b * Hh + h) * Nn + iBase + c);
  }
  // Stage Q: 64h x 128j, de-interleaved into A/B half-tiles.
  #pragma unroll
  for (int k = 0; k < 8; ++k) {
    int q = t + k * 256;
    int h = q >> 5;
    int c = (q & 31) << 2;          // 0..124 step 4
    float4 v = *(const float4*)(Qt + ((size_t)b * Hh + h) * Nn + jBase + c);
    int jq = c >> 3;                // j-octet 0..15
    float* dst = &Qs[((c & 4) ? (64 * 68) : 0) + h * 68 + jq * 4];
    *(float4*)dst = v;
  }

  unsigned long long mask = __ballot(W2[t & 63] >= 0.0f);
  const int nPos = __popcll(mask);
  __syncthreads();

  const int tx = t & 15;   // j-octet
  const int ty = t >> 4;   // i-quad
  const float* prow = &Pl[ty * 4];
  const float* qrowA = &Qs[tx * 4];
  const float* qrowB = qrowA + 64 * 68;

  v2f acc[4][4] = {};
  const v2f zero = {0.0f, 0.0f};
  int h = 0;
  #pragma unroll 4
  for (; h < nPos; ++h) {
    float4 pv = *(const float4*)(prow + h * 68);
    float4 qa = *(const float4*)(qrowA + h * 68);
    float4 qb = *(const float4*)(qrowB + h * 68);
    v2f qj[4] = {{qa.x, qa.y}, {qa.z, qa.w}, {qb.x, qb.y}, {qb.z, qb.w}};
    float p[4] = {pv.x, pv.y, pv.z, pv.w};
    #pragma unroll
    for (int a = 0; a < 4; ++a) {
      v2f ps = {p[a], p[a]};
      #pragma unroll
      for (int c = 0; c < 4; ++c)
        acc[a][c] += __builtin_elementwise_max(ps + qj[c], zero);
    }
  }
  #pragma unroll 4
  for (; h < 64; ++h) {
    float4 pv = *(const float4*)(prow + h * 68);
    float4 qa = *(const float4*)(qrowA + h * 68);
    float4 qb = *(const float4*)(qrowB + h * 68);
    v2f qj[4] = {{qa.x, qa.y}, {qa.z, qa.w}, {qb.x, qb.y}, {qb.z, qb.w}};
    float p[4] = {pv.x, pv.y, pv.z, pv.w};
    #pragma unroll
    for (int a = 0; a < 4; ++a) {
      v2f ps = {p[a], p[a]};
      #pragma unroll
      for (int c = 0; c < 4; ++c)
        acc[a][c] -= __builtin_elementwise_max(ps + qj[c], zero);
    }
  }

  const float b2v = b2[0];
  float* erow = edge + ((size_t)(b * Nn + iBase + ty * 4)) * Nn + jBase + tx * 8;
  #pragma unroll
  for (int a = 0; a < 4; ++a) {
    float4 va = make_float4(acc[a][0].x + b2v, acc[a][0].y + b2v,
                            acc[a][1].x + b2v, acc[a][1].y + b2v);
    float4 vb = make_float4(acc[a][2].x + b2v, acc[a][2].y + b2v,
                            acc[a][3].x + b2v, acc[a][3].y + b2v);
    *(float4*)(erow + (size_t)a * Nn) = va;
    *(float4*)(erow + (size_t)a * Nn + 4) = vb;
  }
}

// ---------------------------------------------------------------------------
// Kernel 3: masked softmax per row, in-place on d_out (unchanged, verified).
// ---------------------------------------------------------------------------
__global__ __launch_bounds__(256)
void k3_softmax(float* __restrict__ out, const int* __restrict__ visited) {
  const int r = blockIdx.x;     // 0..B*N-1
  const int b = r >> 10;
  const int t = threadIdx.x;
  __shared__ float redm[4];
  __shared__ float reds[4];

  const bool vi = visited[r] != 0;
  float* row = out + (size_t)r * Nn;
  const int4 vj = *(const int4*)(visited + b * Nn + t * 4);
  const float4 ev = *(const float4*)(row + t * 4);

  const float NEG = -1000000000.0f;
  float v0 = (vi | (vj.x != 0)) ? NEG : ev.x;
  float v1 = (vi | (vj.y != 0)) ? NEG : ev.y;
  float v2 = (vi | (vj.z != 0)) ? NEG : ev.z;
  float v3 = (vi | (vj.w != 0)) ? NEG : ev.w;

  float m = fmaxf(fmaxf(v0, v1), fmaxf(v2, v3));
  #pragma unroll
  for (int off = 32; off > 0; off >>= 1)
    m = fmaxf(m, __shfl_xor(m, off));
  if ((t & 63) == 0) redm[t >> 6] = m;
  __syncthreads();
  m = fmaxf(fmaxf(redm[0], redm[1]), fmaxf(redm[2], redm[3]));

  float e0 = __expf(v0 - m), e1 = __expf(v1 - m);
  float e2 = __expf(v2 - m), e3 = __expf(v3 - m);
  float s = (e0 + e1) + (e2 + e3);
  #pragma unroll
  for (int off = 32; off > 0; off >>= 1)
    s += __shfl_xor(s, off);
  if ((t & 63) == 0) reds[t >> 6] = s;
  __syncthreads();
  s = (reds[0] + reds[1]) + (reds[2] + reds[3]);

  const float inv = 1.0f / s;
  *(float4*)(row + t * 4) = make_float4(e0 * inv, e1 * inv, e2 * inv, e3 * inv);
}

// ---------------------------------------------------------------------------
extern "C" void kernel_launch(void* const* d_in, const int* in_sizes, int n_in,
                              void* d_out, int out_size, void* d_ws, size_t ws_size,
                              hipStream_t stream) {
  const float* E       = (const float*)d_in[0];  // (B,N,D)
  const int*   visited = (const int*)d_in[1];    // (B,N)
  // d_in[2] remaining_capacity: unused by reference
  const float* W1      = (const float*)d_in[3];  // (H, 2D)
  const float* b1      = (const float*)d_in[4];  // (H,)
  const float* W2      = (const float*)d_in[5];  // (1, H)
  const float* b2      = (const float*)d_in[6];  // (1,)

  float* out = (float*)d_out;                    // (B,N,N)
  float* Pt  = (float*)d_ws;                     // B*H*N floats = 512 KB
  float* Qt  = (float*)((char*)d_ws + (size_t)Bb * Hh * Nn * sizeof(float));

  k1_proj<<<dim3(4, 16, Bb), 256, 0, stream>>>(E, W1, b1, W2, Pt, Qt);
  k2_edge<<<dim3(8, 16, Bb), 256, 0, stream>>>(Pt, Qt, W2, b2, out);
  k3_softmax<<<dim3(Bb * Nn), 256, 0, stream>>>(out, visited);
}